// Round 4
// baseline (1941.030 us; speedup 1.0000x reference)
//
#include <hip/hip_runtime.h>
#include <hip/hip_bf16.h>

// ---------------------------------------------------------------------------
// DRSAR_FL_RNN: B=512, T=128, F=256, H=512, K=3
// R4: column-split scan over 512 WGs (32 batch-groups x 16 col-groups) so the
// transcendental-bound gating work uses all 256 CUs. Per-step h exchange via
// device-coherent (sc0 sc1) global stores in MFMA A-fragment layout +
// per-batch-group monotone flag counters. Wh stays i8 register-resident
// (8 int4 B-frags per wave). gemm1 nn-merged (A-stage amortized over 2x MFMA).
// ---------------------------------------------------------------------------

#define B_  512
#define T_  128
#define F_  256
#define H_  512
#define LOG2E 1.4426950408889634f

typedef __attribute__((ext_vector_type(8))) short short8;
typedef __attribute__((ext_vector_type(4))) float float4v;
typedef __attribute__((ext_vector_type(4))) int int4i;

__device__ inline ushort f2bf(float f) {
  __hip_bfloat16 h = __float2bfloat16(f);
  return *reinterpret_cast<ushort*>(&h);
}
__device__ inline float bf2f(unsigned u) { return __uint_as_float(u << 16); }
__device__ inline float fexp2(float x) { return __builtin_amdgcn_exp2f(x); }
__device__ inline float frcp(float x) { return __builtin_amdgcn_rcpf(x); }

// device-coherent (agent) 16B load: bypasses L1+L2 (sc0 sc1)
__device__ inline int4i load_cohx4(const void* p) {
  int4i r;
  asm volatile("global_load_dwordx4 %0, %1, off sc0 sc1"
               : "=v"(r) : "v"(p) : "memory");
  return r;
}
// device-coherent dword store (write-through to coherent point)
__device__ inline void store_coh(void* p, int v) {
  asm volatile("global_store_dword %0, %1, off sc0 sc1"
               :: "v"(p), "v"(v) : "memory");
}
__device__ inline void waitcnt_vm0() {
  asm volatile("s_waitcnt vmcnt(0)" ::: "memory");
}

// ws layout (bytes):
//   xw2  bf16 frag-linear [T][32 bg][32 nb][64 lane][4 rg] : 0 .. 67108864
//   W2I8 i8 frag-linear [8 kt][32 nb][64 lane][16 B]   : 67108864 (262144)
//   WXF  bf16 frag-linear [8 kt][32 nb][64 lane][8]    : 67371008 (262144)
//   GP8  f32 [512][8]                                  : 67633152 (16384)
//   BVEC f32 [512]                                     : 67649536
//   WCV  f32 [512]                                     : 67651584
//   SCOL f32 [512]                                     : 67653632
//   INVS f32 [512]                                     : 67655680
//   WTS  f32 [256]                                     : 67657728
//   HX   i8 A-frag [2 parity][32 bg][8 kt][1024 B]     : 67659776 (524288)
//   CNT  int [32] (monotone flags)                     : 68184064 (128)
#define WS_W2I8 67108864
#define WS_WXF  67371008
#define WS_GP8  67633152
#define WS_BVEC 67649536
#define WS_WCV  67651584
#define WS_SCOL 67653632
#define WS_INVS 67655680
#define WS_WTS  67657728
#define WS_HX   67659776
#define WS_CNT  68184064

__global__ void prep_misc(const float* __restrict__ theta,
                          const float* __restrict__ Wx,
                          const float* __restrict__ b,
                          const float* __restrict__ c,
                          const float* __restrict__ sigma,
                          const float* __restrict__ q,
                          const float* __restrict__ Wc,
                          float* __restrict__ out_w,
                          ushort* __restrict__ WxF,
                          float* __restrict__ gp8,
                          float* __restrict__ bvec,
                          float* __restrict__ wcv,
                          float* __restrict__ wts) {
  const int i = blockIdx.x * 256 + threadIdx.x;  // 512 blocks -> 131072
  if (i < F_) {
    float w = 1.f / (1.f + __expf(-theta[i]));
    out_w[i] = w;
    wts[i] = w;
  }
  {  // WxF[((kt*32+nb)*64+lane)*8 + j] = bf16(Wx[f][n])
    const int j = i & 7, lane = (i >> 3) & 63, nbkt = i >> 9;
    const int nb = nbkt & 31, kt = nbkt >> 5;
    const int f = kt * 32 + ((lane >> 4) << 3) + j;
    const int n = nb * 16 + (lane & 15);
    WxF[i] = f2bf(Wx[f * H_ + n]);
  }
  if (i < H_) {
    float a[3], cc[3], qq[3];
#pragma unroll
    for (int k = 0; k < 3; ++k) {
      float s = sigma[i * 3 + k];
      cc[k] = c[i * 3 + k];
      a[k] = -LOG2E / (2.f * s * s + 1e-8f);
      qq[k] = q[i * 3 + k];
    }
    gp8[i * 8 + 0] = cc[0];
    gp8[i * 8 + 1] = cc[1];
    gp8[i * 8 + 2] = cc[2];
    gp8[i * 8 + 3] = a[0];
    gp8[i * 8 + 4] = a[1];
    gp8[i * 8 + 5] = a[2];
    gp8[i * 8 + 6] = __uint_as_float((unsigned)f2bf(qq[0]) |
                                     ((unsigned)f2bf(qq[1]) << 16));
    gp8[i * 8 + 7] = __uint_as_float((unsigned)f2bf(qq[2]));
    bvec[i] = b[i];
    wcv[i] = Wc[i];
  }
}

__global__ void scales_kernel(const float* __restrict__ Wh,
                              float* __restrict__ scol,
                              float* __restrict__ invs) {
  const int col = blockIdx.x, lane = threadIdx.x;
  float m = 0.f;
#pragma unroll
  for (int r = 0; r < 8; ++r)
    m = fmaxf(m, fabsf(Wh[(r * 64 + lane) * H_ + col]));
#pragma unroll
  for (int d = 1; d < 64; d <<= 1) m = fmaxf(m, __shfl_xor(m, d, 64));
  if (lane == 0) {
    m = fmaxf(m, 1e-20f);
    scol[col] = m / (127.f * 127.f);
    invs[col] = 127.f / m;
  }
}

__global__ void w2i8_kernel(const float* __restrict__ Wh,
                            const float* __restrict__ invs,
                            int* __restrict__ W2) {
  const int d = blockIdx.x * 256 + threadIdx.x;
  const int dw = d & 3, lane = (d >> 2) & 63, nbkt = d >> 8;
  const int nb = nbkt & 31, kt = nbkt >> 5;
  const int n = nb * 16 + (lane & 15);
  const float iv = invs[n];
  int pk = 0;
#pragma unroll
  for (int jj = 0; jj < 4; ++jj) {
    const int k = kt * 64 + ((lane >> 4) << 4) + dw * 4 + jj;
    int qv = (int)rintf(Wh[k * H_ + n] * iv);
    qv = min(127, max(-127, qv));
    pk |= (qv & 255) << (8 * jj);
  }
  W2[d] = pk;
}

// xw2 = bf16(x*wts) @ bf16(Wx), scan-fragment-linear. grid (t=128, bblk64=8).
__global__ __launch_bounds__(256) void gemm1_kernel(
    const float* __restrict__ x, const float* __restrict__ wts,
    const ushort* __restrict__ WxF, ushort* __restrict__ xw2) {
  __shared__ ushort A[64 * 264];
  const int tid = threadIdx.x;
  const int lane = tid & 63, wg = tid >> 6;
  const int col16 = lane & 15, quad = lane >> 4;
  const int tt = blockIdx.x, bb = blockIdx.y;

  {  // stage A: 64 rows (b=bb*64+r, t=tt) of xf=x*w -> bf16
    const int r = tid >> 2, f0 = (tid & 3) * 64;
    const float4* xp =
        (const float4*)(x + ((size_t)(bb * 64 + r) * T_ + tt) * F_ + f0);
    const float4* wp = (const float4*)(wts + f0);
#pragma unroll
    for (int j = 0; j < 16; ++j) {
      float4 xv = xp[j];
      float4 wv = wp[j];
      ushort4 o;
      o.x = f2bf(xv.x * wv.x);
      o.y = f2bf(xv.y * wv.y);
      o.z = f2bf(xv.z * wv.z);
      o.w = f2bf(xv.w * wv.w);
      *(ushort4*)&A[r * 264 + f0 + j * 4] = o;
    }
  }
  __syncthreads();

  const float4v zero = {0.f, 0.f, 0.f, 0.f};
#pragma unroll
  for (int nn = 0; nn < 2; ++nn) {
    float4v acc[16];
#pragma unroll
    for (int i = 0; i < 16; ++i) acc[i] = zero;
#pragma unroll
    for (int kt = 0; kt < 8; ++kt) {
      short8 af = *(const short8*)&A[(wg * 16 + col16) * 264 + kt * 32 + quad * 8];
#pragma unroll
      for (int nt = 0; nt < 16; ++nt) {
        short8 bf =
            *(const short8*)(WxF + ((kt * 32 + nn * 16 + nt) * 64 + lane) * 8);
        acc[nt] = __builtin_amdgcn_mfma_f32_16x16x32_bf16(af, bf, acc[nt], 0, 0, 0);
      }
    }
#pragma unroll
    for (int nt = 0; nt < 16; ++nt) {
      ushort4 o;
      o.x = f2bf(acc[nt][0]);
      o.y = f2bf(acc[nt][1]);
      o.z = f2bf(acc[nt][2]);
      o.w = f2bf(acc[nt][3]);
      const size_t off =
          (((size_t)tt * 32 + bb * 4 + wg) * 32 + nn * 16 + nt) * 256 +
          (quad * 16 + col16) * 4;
      *(ushort4*)(xw2 + off) = o;
    }
  }
}

// scan2: 512 WGs = 32 bg x 16 cg; 128 thr (2 waves); wave owns 16 h-cols.
__global__ __launch_bounds__(128) void scan2_kernel(
    const ushort* __restrict__ xw2, const int4i* __restrict__ W2,
    const float* __restrict__ gp8, const float* __restrict__ bvec,
    const float* __restrict__ wcv, const float* __restrict__ scol,
    const float* __restrict__ bc, char* __restrict__ hx,
    int* __restrict__ cnt, float* __restrict__ out) {
  const int tid = threadIdx.x;
  const int lane = tid & 63, w = tid >> 6;
  const int col16 = lane & 15, quad = lane >> 4;
  const int bg = blockIdx.x & 31, cg = blockIdx.x >> 5;
  const int nb = cg * 2 + w;                 // global 16-col block
  const int n = nb * 16 + col16;             // this lane's h-column

  // resident Wh i8 B-frags: 8 kt x int4 = 32 VGPRs
  int4i bfr[8];
#pragma unroll
  for (int kt = 0; kt < 8; ++kt) bfr[kt] = W2[(kt * 32 + nb) * 64 + lane];

  const float bcol = bvec[n], scl = scol[n];
  float4v g0 = *(const float4v*)(gp8 + n * 8);
  float4v g1 = *(const float4v*)(gp8 + n * 8 + 4);
  const float c0v = g0[0], c1v = g0[1], c2v = g0[2];
  const float a0v = g0[3], a1v = g1[0], a2v = g1[1];
  unsigned p01 = __float_as_uint(g1[2]);
  const float q0v = bf2f(p01 & 0xffffu);
  const float q1v = bf2f(p01 >> 16);
  const float q2v = bf2f(__float_as_uint(g1[3]) & 0xffffu);

  const unsigned selA = (lane & 1) ? 0x07030501u : 0x02060004u;
  const unsigned selB = (lane & 2) ? 0x07060302u : 0x01000504u;

  // write slot for this wave's transposed h-part (A-frag layout)
  const int ktw = cg >> 1;
  const int qA = (cg & 1) * 2 + w;
  const int wr_off = (bg * 8 + ktw) * 1024 +
                     (qA * 16 + quad * 4 + (col16 & 3)) * 16 + (col16 >> 2) * 4;

  float hreg[4];
#pragma unroll
  for (int rg = 0; rg < 4; ++rg) hreg[rg] = 0.f;

#pragma clang loop unroll(disable)
  for (int t = 0; t < T_; ++t) {
    // xw for this step (independent of exchange)
    ushort4 xv = *(const ushort4*)(xw2 +
                   (((size_t)t * 32 + bg) * 32 + nb) * 256 + lane * 4);

    int4i acc = {0, 0, 0, 0};
    if (t > 0) {
      if (tid == 0) {
        while (__hip_atomic_load(cnt + bg, __ATOMIC_RELAXED,
                                 __HIP_MEMORY_SCOPE_AGENT) < 16 * t)
          __builtin_amdgcn_s_sleep(4);
      }
      __syncthreads();
      // load full A (h_{t-1} for 16 rows x 512 k) as 8 coherent dwordx4
      const char* ab = hx + (((size_t)((t + 1) & 1) * 32 + bg) * 8) * 1024 + lane * 16;
      int4i a0 = load_cohx4(ab);
      int4i a1 = load_cohx4(ab + 1024);
      int4i a2 = load_cohx4(ab + 2048);
      int4i a3 = load_cohx4(ab + 3072);
      int4i a4 = load_cohx4(ab + 4096);
      int4i a5 = load_cohx4(ab + 5120);
      int4i a6 = load_cohx4(ab + 6144);
      int4i a7 = load_cohx4(ab + 7168);
      // tie through waitcnt so MFMA can't be scheduled before the wait
      asm volatile("s_waitcnt vmcnt(0)"
                   : "+v"(a0), "+v"(a1), "+v"(a2), "+v"(a3),
                     "+v"(a4), "+v"(a5), "+v"(a6), "+v"(a7)::"memory");
      acc = __builtin_amdgcn_mfma_i32_16x16x64_i8(a0, bfr[0], acc, 0, 0, 0);
      acc = __builtin_amdgcn_mfma_i32_16x16x64_i8(a1, bfr[1], acc, 0, 0, 0);
      acc = __builtin_amdgcn_mfma_i32_16x16x64_i8(a2, bfr[2], acc, 0, 0, 0);
      acc = __builtin_amdgcn_mfma_i32_16x16x64_i8(a3, bfr[3], acc, 0, 0, 0);
      acc = __builtin_amdgcn_mfma_i32_16x16x64_i8(a4, bfr[4], acc, 0, 0, 0);
      acc = __builtin_amdgcn_mfma_i32_16x16x64_i8(a5, bfr[5], acc, 0, 0, 0);
      acc = __builtin_amdgcn_mfma_i32_16x16x64_i8(a6, bfr[6], acc, 0, 0, 0);
      acc = __builtin_amdgcn_mfma_i32_16x16x64_i8(a7, bfr[7], acc, 0, 0, 0);
    }

    int qb[4];
#pragma unroll
    for (int rg = 0; rg < 4; ++rg) {
      float v = bf2f((unsigned)((const ushort*)&xv)[rg]);
      float z = v + bcol + (float)acc[rg] * scl;
      float e = fexp2(v * (2.f * LOG2E));
      float nw = 1.f - 2.f * frcp(1.f + e);            // tanh(v)
      float d0 = z - c0v, d1 = z - c1v, d2 = z - c2v;
      float m0 = fexp2(d0 * d0 * a0v);
      float m1 = fexp2(d1 * d1 * a1v);
      float m2 = fexp2(d2 * d2 * a2v);
      float num = m0 * q0v + m1 * q1v + m2 * q2v;
      float den = m0 + m1 + m2 + 1e-8f;
      float s = num * frcp(den);
      float gg = frcp(1.f + fexp2(-s * LOG2E));        // sigmoid(s)
      float h = hreg[rg] + gg * (nw - hreg[rg]);
      hreg[rg] = h;
      qb[rg] = (int)rintf(h * 127.f);
    }

    if (t < T_ - 1) {
      int pk = (qb[0] & 255) | ((qb[1] & 255) << 8) | ((qb[2] & 255) << 16) |
               (qb[3] << 24);
      // 16x16 i8 in-wave transpose (C-layout -> A-layout dwords)
      int p1 = __shfl_xor(pk, 1, 64);
      int Aw = __builtin_amdgcn_perm((unsigned)pk, (unsigned)p1, selA);
      int p2 = __shfl_xor(Aw, 2, 64);
      int Tw = __builtin_amdgcn_perm((unsigned)Aw, (unsigned)p2, selB);
      char* dst = hx + ((size_t)(t & 1) * 32) * 8192 + wr_off;
      store_coh(dst, Tw);
      waitcnt_vm0();
      __syncthreads();             // all 128 threads' stores are visible
      if (tid == 0)
        atomicAdd(cnt + bg, 1);    // device-scope flag
    }
  }

  // logits: partial over this wave's 16 cols -> atomicAdd
  const float wc = wcv[n];
  float part[4];
#pragma unroll
  for (int rg = 0; rg < 4; ++rg) {
    part[rg] = hreg[rg] * wc;
#pragma unroll
    for (int m = 1; m < 16; m <<= 1) part[rg] += __shfl_xor(part[rg], m, 64);
  }
  if (col16 == 0) {
    float add_bc = (cg == 0 && w == 0) ? bc[0] : 0.f;
#pragma unroll
    for (int rg = 0; rg < 4; ++rg)
      atomicAdd(out + bg * 16 + quad * 4 + rg, part[rg] + add_bc * 0.25f * 0.f);
    if (cg == 0 && w == 0 && quad == 0) {
      // add bc once per row handled below instead
    }
  }
  // bc: add once per batch row by (cg==0, w==0) wave's quad leaders
  if (cg == 0 && w == 0 && col16 == 0) {
#pragma unroll
    for (int rg = 0; rg < 4; ++rg)
      atomicAdd(out + bg * 16 + quad * 4 + rg, bc[0]);
  }
}

extern "C" void kernel_launch(void* const* d_in, const int* in_sizes, int n_in,
                              void* d_out, int out_size, void* d_ws, size_t ws_size,
                              hipStream_t stream) {
  const float* x     = (const float*)d_in[0];
  const float* theta = (const float*)d_in[1];
  const float* Wx    = (const float*)d_in[2];
  const float* Wh    = (const float*)d_in[3];
  const float* b     = (const float*)d_in[4];
  const float* c     = (const float*)d_in[5];
  const float* sigma = (const float*)d_in[6];
  const float* q     = (const float*)d_in[7];
  const float* Wc    = (const float*)d_in[8];
  const float* bc    = (const float*)d_in[9];
  float* out = (float*)d_out;

  ushort* xw2 = (ushort*)d_ws;
  int*    W2  = (int*)((char*)d_ws + WS_W2I8);
  ushort* WxF = (ushort*)((char*)d_ws + WS_WXF);
  float*  gp8 = (float*)((char*)d_ws + WS_GP8);
  float*  bv  = (float*)((char*)d_ws + WS_BVEC);
  float*  wcv = (float*)((char*)d_ws + WS_WCV);
  float*  scl = (float*)((char*)d_ws + WS_SCOL);
  float*  inv = (float*)((char*)d_ws + WS_INVS);
  float*  wts = (float*)((char*)d_ws + WS_WTS);
  char*   hx  = (char*)d_ws + WS_HX;
  int*    cnt = (int*)((char*)d_ws + WS_CNT);

  hipMemsetAsync(out, 0, B_ * sizeof(float), stream);
  hipMemsetAsync(cnt, 0, 128, stream);
  hipLaunchKernelGGL(prep_misc, dim3(512), dim3(256), 0, stream,
                     theta, Wx, b, c, sigma, q, Wc, out + B_, WxF, gp8, bv, wcv, wts);
  hipLaunchKernelGGL(scales_kernel, dim3(512), dim3(64), 0, stream, Wh, scl, inv);
  hipLaunchKernelGGL(w2i8_kernel, dim3(256), dim3(256), 0, stream, Wh, inv, W2);
  hipLaunchKernelGGL(gemm1_kernel, dim3(128, 8), dim3(256), 0, stream,
                     x, wts, WxF, xw2);
  hipLaunchKernelGGL(scan2_kernel, dim3(512), dim3(128), 0, stream,
                     xw2, (const int4i*)W2, gp8, bv, wcv, scl, bc, hx, cnt, out);
}

// Round 6
// 507.654 us; speedup vs baseline: 3.8235x; 3.8235x over previous
//
#include <hip/hip_runtime.h>
#include <hip/hip_bf16.h>

// ---------------------------------------------------------------------------
// DRSAR_FL_RNN: B=512, T=128, F=256, H=512, K=3
// R6 = R5 with the xw prefetch stride bug fixed (per-t slab is 262144
// ushorts, not 32768 — scan3 was consuming wrong-timestep xw for t>0).
//   (a) 64 WGs x 8 batch rows (MFMA M=16 half-wasted; MFMA is ~4% of budget)
//       with quad-swap shuffle so all 64 lanes do real gating work.
//   (b) double-buffered LDS h-mirror -> ONE __syncthreads per step.
// ---------------------------------------------------------------------------

#define B_  512
#define T_  128
#define F_  256
#define H_  512
#define LOG2E 1.4426950408889634f

// xw2 per-timestep stride in ushorts: [64 bg][8 w][512 el]
#define XW_T_STRIDE 262144

typedef __attribute__((ext_vector_type(8))) short short8;
typedef __attribute__((ext_vector_type(4))) float float4v;
typedef __attribute__((ext_vector_type(4))) int int4i;

__device__ inline ushort f2bf(float f) {
  __hip_bfloat16 h = __float2bfloat16(f);
  return *reinterpret_cast<ushort*>(&h);
}
__device__ inline float bf2f(unsigned u) { return __uint_as_float(u << 16); }
__device__ inline float fexp2(float x) { return __builtin_amdgcn_exp2f(x); }
__device__ inline float frcp(float x) { return __builtin_amdgcn_rcpf(x); }

// ws layout (bytes):
//   xw2  bf16 scan-frag-linear [T][64 bg][8 w][64 lane][8 el] : 0 .. 67108864
//   W2I8 i8 frag-linear [8 kt][32 nb][64 lane][16 B]   : 67108864 (262144)
//   WXF  bf16 frag-linear [8 kt][32 nb][64 lane][8]    : 67371008 (262144)
//   GP8  f32 [512][8]                                  : 67633152 (16384)
//   BVEC f32 [512]                                     : 67649536
//   WCV  f32 [512]                                     : 67651584
//   SCOL f32 [512]                                     : 67653632
//   INVS f32 [512]                                     : 67655680
//   WTS  f32 [256]                                     : 67657728
#define WS_W2I8 67108864
#define WS_WXF  67371008
#define WS_GP8  67633152
#define WS_BVEC 67649536
#define WS_WCV  67651584
#define WS_SCOL 67653632
#define WS_INVS 67655680
#define WS_WTS  67657728

__global__ void prep_misc(const float* __restrict__ theta,
                          const float* __restrict__ Wx,
                          const float* __restrict__ b,
                          const float* __restrict__ c,
                          const float* __restrict__ sigma,
                          const float* __restrict__ q,
                          const float* __restrict__ Wc,
                          float* __restrict__ out_w,
                          ushort* __restrict__ WxF,
                          float* __restrict__ gp8,
                          float* __restrict__ bvec,
                          float* __restrict__ wcv,
                          float* __restrict__ wts) {
  const int i = blockIdx.x * 256 + threadIdx.x;  // 512 blocks -> 131072
  if (i < F_) {
    float w = 1.f / (1.f + __expf(-theta[i]));
    out_w[i] = w;
    wts[i] = w;
  }
  {  // WxF[((kt*32+nb)*64+lane)*8 + j] = bf16(Wx[f][n])
    const int j = i & 7, lane = (i >> 3) & 63, nbkt = i >> 9;
    const int nb = nbkt & 31, kt = nbkt >> 5;
    const int f = kt * 32 + ((lane >> 4) << 3) + j;
    const int n = nb * 16 + (lane & 15);
    WxF[i] = f2bf(Wx[f * H_ + n]);
  }
  if (i < H_) {
    float a[3], cc[3], qq[3];
#pragma unroll
    for (int k = 0; k < 3; ++k) {
      float s = sigma[i * 3 + k];
      cc[k] = c[i * 3 + k];
      a[k] = -LOG2E / (2.f * s * s + 1e-8f);
      qq[k] = q[i * 3 + k];
    }
    gp8[i * 8 + 0] = cc[0];
    gp8[i * 8 + 1] = cc[1];
    gp8[i * 8 + 2] = cc[2];
    gp8[i * 8 + 3] = a[0];
    gp8[i * 8 + 4] = a[1];
    gp8[i * 8 + 5] = a[2];
    gp8[i * 8 + 6] = __uint_as_float((unsigned)f2bf(qq[0]) |
                                     ((unsigned)f2bf(qq[1]) << 16));
    gp8[i * 8 + 7] = __uint_as_float((unsigned)f2bf(qq[2]));
    bvec[i] = b[i];
    wcv[i] = Wc[i];
  }
}

__global__ void scales_kernel(const float* __restrict__ Wh,
                              float* __restrict__ scol,
                              float* __restrict__ invs) {
  const int col = blockIdx.x, lane = threadIdx.x;
  float m = 0.f;
#pragma unroll
  for (int r = 0; r < 8; ++r)
    m = fmaxf(m, fabsf(Wh[(r * 64 + lane) * H_ + col]));
#pragma unroll
  for (int d = 1; d < 64; d <<= 1) m = fmaxf(m, __shfl_xor(m, d, 64));
  if (lane == 0) {
    m = fmaxf(m, 1e-20f);
    scol[col] = m / (127.f * 127.f);
    invs[col] = 127.f / m;
  }
}

__global__ void w2i8_kernel(const float* __restrict__ Wh,
                            const float* __restrict__ invs,
                            int* __restrict__ W2) {
  const int d = blockIdx.x * 256 + threadIdx.x;
  const int dw = d & 3, lane = (d >> 2) & 63, nbkt = d >> 8;
  const int nb = nbkt & 31, kt = nbkt >> 5;
  const int n = nb * 16 + (lane & 15);
  const float iv = invs[n];
  int pk = 0;
#pragma unroll
  for (int jj = 0; jj < 4; ++jj) {
    const int k = kt * 64 + ((lane >> 4) << 4) + dw * 4 + jj;
    int qv = (int)rintf(Wh[k * H_ + n] * iv);
    qv = min(127, max(-127, qv));
    pk |= (qv & 255) << (8 * jj);
  }
  W2[d] = pk;
}

// xw2 = bf16(x*wts) @ bf16(Wx), stored in scan3's fragment layout.
// grid (t=128, bblk64=8), 256 thr.
__global__ __launch_bounds__(256) void gemm1_kernel(
    const float* __restrict__ x, const float* __restrict__ wts,
    const ushort* __restrict__ WxF, ushort* __restrict__ xw2) {
  __shared__ ushort A[64 * 264];
  const int tid = threadIdx.x;
  const int lane = tid & 63, wg = tid >> 6;
  const int col16 = lane & 15, quad = lane >> 4;
  const int tt = blockIdx.x, bb = blockIdx.y;

  {  // stage A: 64 rows (b=bb*64+r, t=tt) of xf=x*w -> bf16
    const int r = tid >> 2, f0 = (tid & 3) * 64;
    const float4* xp =
        (const float4*)(x + ((size_t)(bb * 64 + r) * T_ + tt) * F_ + f0);
    const float4* wp = (const float4*)(wts + f0);
#pragma unroll
    for (int j = 0; j < 16; ++j) {
      float4 xv = xp[j];
      float4 wv = wp[j];
      ushort4 o;
      o.x = f2bf(xv.x * wv.x);
      o.y = f2bf(xv.y * wv.y);
      o.z = f2bf(xv.z * wv.z);
      o.w = f2bf(xv.w * wv.w);
      *(ushort4*)&A[r * 264 + f0 + j * 4] = o;
    }
  }
  __syncthreads();

  const float4v zero = {0.f, 0.f, 0.f, 0.f};
#pragma unroll
  for (int nn = 0; nn < 2; ++nn) {
    float4v acc[16];
#pragma unroll
    for (int i = 0; i < 16; ++i) acc[i] = zero;
#pragma unroll
    for (int kt = 0; kt < 8; ++kt) {
      short8 af = *(const short8*)&A[(wg * 16 + col16) * 264 + kt * 32 + quad * 8];
#pragma unroll
      for (int nt = 0; nt < 16; ++nt) {
        short8 bf =
            *(const short8*)(WxF + ((kt * 32 + nn * 16 + nt) * 64 + lane) * 8);
        acc[nt] = __builtin_amdgcn_mfma_f32_16x16x32_bf16(af, bf, acc[nt], 0, 0, 0);
      }
    }
    // store into scan3 layout:
    //   element (row R = bb*64+wg*16+quad*4+rg, col c = nn*256+nt*16+col16)
    //   bg = R>>3 ; r = R&7 ; w_s = c>>6 ; nt_s = (c>>4)&3
    //   quad_s = 2*(nt_s>=2) + (r>=4) ; el = (nt_s&1)*4 + (r&3)
    //   xw2[ (t*262144) + (bg*8 + w_s)*512 + (quad_s*16+col16)*8 + el ]
#pragma unroll
    for (int nt = 0; nt < 16; ++nt) {
      ushort4 o;
      o.x = f2bf(acc[nt][0]);
      o.y = f2bf(acc[nt][1]);
      o.z = f2bf(acc[nt][2]);
      o.w = f2bf(acc[nt][3]);
      const int bg = bb * 8 + wg * 2 + (quad >> 1);
      const int w_s = nn * 4 + (nt >> 2);
      const int nt_s = nt & 3;
      const int quad_s = ((nt_s & 2) ? 2 : 0) + (quad & 1);
      const size_t off = (size_t)tt * XW_T_STRIDE + ((size_t)bg * 8 + w_s) * 512 +
                         (quad_s * 16 + col16) * 8 + (nt_s & 1) * 4;
      *(ushort4*)(xw2 + off) = o;
    }
  }
}

// scan3: 64 WGs x 512 thr (8 waves); WG owns 8 batch rows; wave owns 64 cols.
// Quad-swap: quads 0,1 process nt 0,1 (rows 0-3 / 4-7); quads 2,3 process
// nt 2,3 via shfl_xor(acc,32). Double-buffered LDS h-mirror, 1 barrier/step.
__global__ __launch_bounds__(512, 2) void scan3_kernel(
    const ushort* __restrict__ xw2, const int4i* __restrict__ W2,
    const float* __restrict__ gp8, const float* __restrict__ bvec,
    const float* __restrict__ wcv, const float* __restrict__ scol,
    const float* __restrict__ bc, float* __restrict__ out) {
  __shared__ int hl4[2 * 16 * 132];  // two h i8 mirrors: 16 rows x 528 B
  __shared__ float red[8][8];
  const int tid = threadIdx.x;
  const int lane = tid & 63, w = tid >> 6;
  const int col16 = lane & 15, quad = lane >> 4;
  const int bg = blockIdx.x;

  for (int i = tid; i < 2 * 16 * 132; i += 512) hl4[i] = 0;

  // resident Wh i8 B-frags: 8 kt x 4 nt x int4 = 128 regs
  int4i bfr[8][4];
#pragma unroll
  for (int kt = 0; kt < 8; ++kt)
#pragma unroll
    for (int nt = 0; nt < 4; ++nt)
      bfr[kt][nt] = W2[(kt * 32 + w * 4 + nt) * 64 + lane];

  // this lane's two gating columns (after quad-swap): base nt = quad&2
  const int base = (quad & 2);
  int cols[2];
  float bcol[2], scl[2], wcl[2];
  float c0v[2], c1v[2], c2v[2], a0v[2], a1v[2], a2v[2], q0v[2], q1v[2], q2v[2];
#pragma unroll
  for (int j = 0; j < 2; ++j) {
    cols[j] = w * 64 + (base + j) * 16 + col16;
    bcol[j] = bvec[cols[j]];
    scl[j] = scol[cols[j]];
    wcl[j] = wcv[cols[j]];
    float4v g0 = *(const float4v*)(gp8 + cols[j] * 8);
    float4v g1 = *(const float4v*)(gp8 + cols[j] * 8 + 4);
    c0v[j] = g0[0]; c1v[j] = g0[1]; c2v[j] = g0[2];
    a0v[j] = g0[3]; a1v[j] = g1[0]; a2v[j] = g1[1];
    unsigned p01 = __float_as_uint(g1[2]);
    q0v[j] = bf2f(p01 & 0xffffu);
    q1v[j] = bf2f(p01 >> 16);
    q2v[j] = bf2f(__float_as_uint(g1[3]) & 0xffffu);
  }
  const unsigned selA = (lane & 1) ? 0x07030501u : 0x02060004u;
  const unsigned selB = (lane & 2) ? 0x07060302u : 0x01000504u;

  float hreg[2][4];
#pragma unroll
  for (int j = 0; j < 2; ++j)
#pragma unroll
    for (int rg = 0; rg < 4; ++rg) hreg[j][rg] = 0.f;

  // xw slab: per (t,bg): 8 w x 64 lane x 8 el ushorts; lane loads 16 B
  const ushort* xwb = xw2 + ((size_t)bg * 8 + w) * 512 + lane * 8;
  int4i xv = *(const int4i*)xwb;
  int4i xn;
  __syncthreads();

#pragma clang loop unroll(disable)
  for (int t = 0; t < T_; ++t) {
    const int tn = (t + 1) & 127;
    xn = *(const int4i*)(xwb + (size_t)tn * XW_T_STRIDE);

    const char* bufr = (const char*)(hl4 + (t & 1) * 2112);
    int4i acc[4];
    const int4i izero = {0, 0, 0, 0};
#pragma unroll
    for (int nt = 0; nt < 4; ++nt) acc[nt] = izero;
#pragma unroll
    for (int kt = 0; kt < 8; ++kt) {
      int4i a = *(const int4i*)(bufr + col16 * 528 + kt * 64 + quad * 16);
#pragma unroll
      for (int nt = 0; nt < 4; ++nt)
        acc[nt] = __builtin_amdgcn_mfma_i32_16x16x64_i8(a, bfr[kt][nt], acc[nt], 0, 0, 0);
    }
    // quad-swap: hand nt 2,3 (rows 0-7) to quads 2,3
    int4i s2, s3;
#pragma unroll
    for (int d = 0; d < 4; ++d) {
      s2[d] = __shfl_xor(acc[2][d], 32, 64);
      s3[d] = __shfl_xor(acc[3][d], 32, 64);
    }
    int4i accJ[2];
    accJ[0] = (quad & 2) ? s2 : acc[0];
    accJ[1] = (quad & 2) ? s3 : acc[1];

    int pk[2];
#pragma unroll
    for (int j = 0; j < 2; ++j) {
      int qb[4];
#pragma unroll
      for (int rg = 0; rg < 4; ++rg) {
        const int us = j * 4 + rg;
        unsigned dwv = (unsigned)xv[us >> 1];
        float v = __uint_as_float((us & 1) ? (dwv & 0xffff0000u) : (dwv << 16));
        float z = v + bcol[j] + (float)accJ[j][rg] * scl[j];
        float e = fexp2(v * (2.f * LOG2E));
        float nw = 1.f - 2.f * frcp(1.f + e);          // tanh(v)
        float d0 = z - c0v[j], d1 = z - c1v[j], d2 = z - c2v[j];
        float m0 = fexp2(d0 * d0 * a0v[j]);
        float m1 = fexp2(d1 * d1 * a1v[j]);
        float m2 = fexp2(d2 * d2 * a2v[j]);
        float num = m0 * q0v[j] + m1 * q1v[j] + m2 * q2v[j];
        float den = m0 + m1 + m2 + 1e-8f;
        float s = num * frcp(den);
        float gg = frcp(1.f + fexp2(-s * LOG2E));      // sigmoid(s)
        float h = hreg[j][rg] + gg * (nw - hreg[j][rg]);
        hreg[j][rg] = h;
        qb[rg] = (int)rintf(h * 127.f);
      }
      pk[j] = (qb[0] & 255) | ((qb[1] & 255) << 8) | ((qb[2] & 255) << 16) |
              (qb[3] << 24);
    }

    if (t < T_ - 1) {
      // un-swap: quads 0,1 gather nt 2,3 results back
      int r0 = __shfl_xor(pk[0], 32, 64);
      int r1 = __shfl_xor(pk[1], 32, 64);
      int pks[4] = {pk[0], pk[1], r0, r1};
      int* bufw = hl4 + (((t + 1) & 1) * 2112);
#pragma unroll
      for (int nt = 0; nt < 4; ++nt) {
        int p1 = __shfl_xor(pks[nt], 1, 64);
        int Aw = __builtin_amdgcn_perm((unsigned)pks[nt], (unsigned)p1, selA);
        int p2 = __shfl_xor(Aw, 2, 64);
        int Tw = __builtin_amdgcn_perm((unsigned)Aw, (unsigned)p2, selB);
        if (quad < 2)
          bufw[(quad * 4 + (col16 & 3)) * 132 + w * 16 + nt * 4 + (col16 >> 2)] = Tw;
      }
      __syncthreads();
    }
    xv = xn;
  }

  // logits: row r = (quad&1)*4 + rg
  float part[4];
#pragma unroll
  for (int rg = 0; rg < 4; ++rg) {
    part[rg] = hreg[0][rg] * wcl[0] + hreg[1][rg] * wcl[1];
    part[rg] += __shfl_xor(part[rg], 32, 64);
#pragma unroll
    for (int m = 1; m < 16; m <<= 1) part[rg] += __shfl_xor(part[rg], m, 64);
  }
  if (quad < 2 && col16 == 0) {
#pragma unroll
    for (int rg = 0; rg < 4; ++rg) red[w][(quad & 1) * 4 + rg] = part[rg];
  }
  __syncthreads();
  if (tid < 8) {
    float s = bc[0];
#pragma unroll
    for (int ww = 0; ww < 8; ++ww) s += red[ww][tid];
    out[bg * 8 + tid] = s;
  }
}

extern "C" void kernel_launch(void* const* d_in, const int* in_sizes, int n_in,
                              void* d_out, int out_size, void* d_ws, size_t ws_size,
                              hipStream_t stream) {
  const float* x     = (const float*)d_in[0];
  const float* theta = (const float*)d_in[1];
  const float* Wx    = (const float*)d_in[2];
  const float* Wh    = (const float*)d_in[3];
  const float* b     = (const float*)d_in[4];
  const float* c     = (const float*)d_in[5];
  const float* sigma = (const float*)d_in[6];
  const float* q     = (const float*)d_in[7];
  const float* Wc    = (const float*)d_in[8];
  const float* bc    = (const float*)d_in[9];
  float* out = (float*)d_out;

  ushort* xw2 = (ushort*)d_ws;
  int*    W2  = (int*)((char*)d_ws + WS_W2I8);
  ushort* WxF = (ushort*)((char*)d_ws + WS_WXF);
  float*  gp8 = (float*)((char*)d_ws + WS_GP8);
  float*  bv  = (float*)((char*)d_ws + WS_BVEC);
  float*  wcv = (float*)((char*)d_ws + WS_WCV);
  float*  scl = (float*)((char*)d_ws + WS_SCOL);
  float*  inv = (float*)((char*)d_ws + WS_INVS);
  float*  wts = (float*)((char*)d_ws + WS_WTS);

  hipLaunchKernelGGL(prep_misc, dim3(512), dim3(256), 0, stream,
                     theta, Wx, b, c, sigma, q, Wc, out + B_, WxF, gp8, bv, wcv, wts);
  hipLaunchKernelGGL(scales_kernel, dim3(512), dim3(64), 0, stream, Wh, scl, inv);
  hipLaunchKernelGGL(w2i8_kernel, dim3(256), dim3(256), 0, stream, Wh, inv, W2);
  hipLaunchKernelGGL(gemm1_kernel, dim3(128, 8), dim3(256), 0, stream,
                     x, wts, WxF, xw2);
  hipLaunchKernelGGL(scan3_kernel, dim3(64), dim3(512), 0, stream,
                     xw2, (const int4i*)W2, gp8, bv, wcv, scl, bc, out);
}

// Round 7
// 368.407 us; speedup vs baseline: 5.2687x; 1.3780x over previous
//
#include <hip/hip_runtime.h>
#include <hip/hip_bf16.h>

// ---------------------------------------------------------------------------
// DRSAR_FL_RNN: B=512, T=128, F=256, H=512, K=3
// R7 = R6 scaled to ALL 256 CUs: 256 WGs x 2 batch rows (MFMA M=16 is 7/8
// padding - MFMA chains are ~20% local and redundant M-work is free vs the
// VALU win). Quad-spread via 8 shfl + selects; each lane owns ONE h-column,
// gating 2 el/lane. Double-buffered LDS h-mirror (rows 2-15 always zero),
// one barrier/step. xw2 relaid [t][256bg][8w][64lane][2el].
// ---------------------------------------------------------------------------

#define B_  512
#define T_  128
#define F_  256
#define H_  512
#define LOG2E 1.4426950408889634f

// xw2 per-timestep stride in ushorts: [256 bg][8 w][64 lane][2 el]
#define XW_T_STRIDE 262144

typedef __attribute__((ext_vector_type(8))) short short8;
typedef __attribute__((ext_vector_type(4))) float float4v;
typedef __attribute__((ext_vector_type(4))) int int4i;

__device__ inline ushort f2bf(float f) {
  __hip_bfloat16 h = __float2bfloat16(f);
  return *reinterpret_cast<ushort*>(&h);
}
__device__ inline float bf2f(unsigned u) { return __uint_as_float(u << 16); }
__device__ inline float fexp2(float x) { return __builtin_amdgcn_exp2f(x); }
__device__ inline float frcp(float x) { return __builtin_amdgcn_rcpf(x); }

// ws layout (bytes):
//   xw2  bf16 [T][256 bg][8 w][64 lane][2 el]          : 0 .. 67108864
//   W2I8 i8 frag-linear [8 kt][32 nb][64 lane][16 B]   : 67108864 (262144)
//   WXF  bf16 frag-linear [8 kt][32 nb][64 lane][8]    : 67371008 (262144)
//   GP8  f32 [512][8]                                  : 67633152 (16384)
//   BVEC f32 [512]                                     : 67649536
//   WCV  f32 [512]                                     : 67651584
//   SCOL f32 [512]                                     : 67653632
//   INVS f32 [512]                                     : 67655680
//   WTS  f32 [256]                                     : 67657728
#define WS_W2I8 67108864
#define WS_WXF  67371008
#define WS_GP8  67633152
#define WS_BVEC 67649536
#define WS_WCV  67651584
#define WS_SCOL 67653632
#define WS_INVS 67655680
#define WS_WTS  67657728

__global__ void prep_misc(const float* __restrict__ theta,
                          const float* __restrict__ Wx,
                          const float* __restrict__ b,
                          const float* __restrict__ c,
                          const float* __restrict__ sigma,
                          const float* __restrict__ q,
                          const float* __restrict__ Wc,
                          float* __restrict__ out_w,
                          ushort* __restrict__ WxF,
                          float* __restrict__ gp8,
                          float* __restrict__ bvec,
                          float* __restrict__ wcv,
                          float* __restrict__ wts) {
  const int i = blockIdx.x * 256 + threadIdx.x;  // 512 blocks -> 131072
  if (i < F_) {
    float w = 1.f / (1.f + __expf(-theta[i]));
    out_w[i] = w;
    wts[i] = w;
  }
  {  // WxF[((kt*32+nb)*64+lane)*8 + j] = bf16(Wx[f][n])
    const int j = i & 7, lane = (i >> 3) & 63, nbkt = i >> 9;
    const int nb = nbkt & 31, kt = nbkt >> 5;
    const int f = kt * 32 + ((lane >> 4) << 3) + j;
    const int n = nb * 16 + (lane & 15);
    WxF[i] = f2bf(Wx[f * H_ + n]);
  }
  if (i < H_) {
    float a[3], cc[3], qq[3];
#pragma unroll
    for (int k = 0; k < 3; ++k) {
      float s = sigma[i * 3 + k];
      cc[k] = c[i * 3 + k];
      a[k] = -LOG2E / (2.f * s * s + 1e-8f);
      qq[k] = q[i * 3 + k];
    }
    gp8[i * 8 + 0] = cc[0];
    gp8[i * 8 + 1] = cc[1];
    gp8[i * 8 + 2] = cc[2];
    gp8[i * 8 + 3] = a[0];
    gp8[i * 8 + 4] = a[1];
    gp8[i * 8 + 5] = a[2];
    gp8[i * 8 + 6] = __uint_as_float((unsigned)f2bf(qq[0]) |
                                     ((unsigned)f2bf(qq[1]) << 16));
    gp8[i * 8 + 7] = __uint_as_float((unsigned)f2bf(qq[2]));
    bvec[i] = b[i];
    wcv[i] = Wc[i];
  }
}

__global__ void scales_kernel(const float* __restrict__ Wh,
                              float* __restrict__ scol,
                              float* __restrict__ invs) {
  const int col = blockIdx.x, lane = threadIdx.x;
  float m = 0.f;
#pragma unroll
  for (int r = 0; r < 8; ++r)
    m = fmaxf(m, fabsf(Wh[(r * 64 + lane) * H_ + col]));
#pragma unroll
  for (int d = 1; d < 64; d <<= 1) m = fmaxf(m, __shfl_xor(m, d, 64));
  if (lane == 0) {
    m = fmaxf(m, 1e-20f);
    scol[col] = m / (127.f * 127.f);
    invs[col] = 127.f / m;
  }
}

__global__ void w2i8_kernel(const float* __restrict__ Wh,
                            const float* __restrict__ invs,
                            int* __restrict__ W2) {
  const int d = blockIdx.x * 256 + threadIdx.x;
  const int dw = d & 3, lane = (d >> 2) & 63, nbkt = d >> 8;
  const int nb = nbkt & 31, kt = nbkt >> 5;
  const int n = nb * 16 + (lane & 15);
  const float iv = invs[n];
  int pk = 0;
#pragma unroll
  for (int jj = 0; jj < 4; ++jj) {
    const int k = kt * 64 + ((lane >> 4) << 4) + dw * 4 + jj;
    int qv = (int)rintf(Wh[k * H_ + n] * iv);
    qv = min(127, max(-127, qv));
    pk |= (qv & 255) << (8 * jj);
  }
  W2[d] = pk;
}

// xw2 = bf16(x*wts) @ bf16(Wx), stored in scan4's layout.
// grid (t=128, bblk64=8), 256 thr.
__global__ __launch_bounds__(256) void gemm1_kernel(
    const float* __restrict__ x, const float* __restrict__ wts,
    const ushort* __restrict__ WxF, ushort* __restrict__ xw2) {
  __shared__ ushort A[64 * 264];
  const int tid = threadIdx.x;
  const int lane = tid & 63, wg = tid >> 6;
  const int col16 = lane & 15, quad = lane >> 4;
  const int tt = blockIdx.x, bb = blockIdx.y;

  {  // stage A: 64 rows (b=bb*64+r, t=tt) of xf=x*w -> bf16
    const int r = tid >> 2, f0 = (tid & 3) * 64;
    const float4* xp =
        (const float4*)(x + ((size_t)(bb * 64 + r) * T_ + tt) * F_ + f0);
    const float4* wp = (const float4*)(wts + f0);
#pragma unroll
    for (int j = 0; j < 16; ++j) {
      float4 xv = xp[j];
      float4 wv = wp[j];
      ushort4 o;
      o.x = f2bf(xv.x * wv.x);
      o.y = f2bf(xv.y * wv.y);
      o.z = f2bf(xv.z * wv.z);
      o.w = f2bf(xv.w * wv.w);
      *(ushort4*)&A[r * 264 + f0 + j * 4] = o;
    }
  }
  __syncthreads();

  const float4v zero = {0.f, 0.f, 0.f, 0.f};
#pragma unroll
  for (int nn = 0; nn < 2; ++nn) {
    float4v acc[16];
#pragma unroll
    for (int i = 0; i < 16; ++i) acc[i] = zero;
#pragma unroll
    for (int kt = 0; kt < 8; ++kt) {
      short8 af = *(const short8*)&A[(wg * 16 + col16) * 264 + kt * 32 + quad * 8];
#pragma unroll
      for (int nt = 0; nt < 16; ++nt) {
        short8 bf =
            *(const short8*)(WxF + ((kt * 32 + nn * 16 + nt) * 64 + lane) * 8);
        acc[nt] = __builtin_amdgcn_mfma_f32_16x16x32_bf16(af, bf, acc[nt], 0, 0, 0);
      }
    }
    // store into scan4 layout:
    //   element (R = bb*64+wg*16+quad*4+rg, c = nn*256+nt*16+col16)
    //   bg = R>>1, el = R&1 = rg&1; w_s = nn*4+(nt>>2); lane_s = (nt&3)*16+col16
    //   off = (((t*256 + bg)*8 + w_s)*64 + lane_s)*2 + el
#pragma unroll
    for (int nt = 0; nt < 16; ++nt) {
      ushort2 lo, hi;
      lo.x = f2bf(acc[nt][0]);
      lo.y = f2bf(acc[nt][1]);
      hi.x = f2bf(acc[nt][2]);
      hi.y = f2bf(acc[nt][3]);
      const int bg0 = bb * 32 + wg * 8 + quad * 2;
      const size_t off0 =
          (((size_t)tt * 256 + bg0) * 8 + nn * 4 + (nt >> 2)) * 128 +
          ((nt & 3) * 16 + col16) * 2;
      *(ushort2*)(xw2 + off0) = lo;
      *(ushort2*)(xw2 + off0 + 1024) = hi;  // bg0+1 -> +8*128 ushorts
    }
  }
}

// scan4: 256 WGs x 512 thr (8 waves); WG owns 2 batch rows; wave owns 64
// cols (4 nt). Quad-spread: quad q takes nt q via shfl-from-quad0 + selects;
// each lane owns ONE h-column, 2 elements. Double-buffered LDS h-mirror
// (16 rows x 528 B; rows 2-15 permanently zero), one barrier/step.
__global__ __launch_bounds__(512, 2) void scan4_kernel(
    const ushort* __restrict__ xw2, const int4i* __restrict__ W2,
    const float* __restrict__ gp8, const float* __restrict__ bvec,
    const float* __restrict__ wcv, const float* __restrict__ scol,
    const float* __restrict__ bc, float* __restrict__ out) {
  __shared__ int hl4[2 * 16 * 132];  // two h i8 mirrors: 16 rows x 528 B
  __shared__ float red[8][2];
  const int tid = threadIdx.x;
  const int lane = tid & 63, w = tid >> 6;
  const int col16 = lane & 15, quad = lane >> 4;
  const int bg = blockIdx.x;

  for (int i = tid; i < 2 * 16 * 132; i += 512) hl4[i] = 0;

  // resident Wh i8 B-frags: 8 kt x 4 nt x int4 = 128 regs
  int4i bfr[8][4];
#pragma unroll
  for (int kt = 0; kt < 8; ++kt)
#pragma unroll
    for (int nt = 0; nt < 4; ++nt)
      bfr[kt][nt] = W2[(kt * 32 + w * 4 + nt) * 64 + lane];

  // this lane's single gating column
  const int col = w * 64 + lane;  // = w*64 + quad*16 + col16
  const float bcol = bvec[col], scl = scol[col], wcl = wcv[col];
  float4v g0 = *(const float4v*)(gp8 + col * 8);
  float4v g1 = *(const float4v*)(gp8 + col * 8 + 4);
  const float c0v = g0[0], c1v = g0[1], c2v = g0[2];
  const float a0v = g0[3], a1v = g1[0], a2v = g1[1];
  unsigned p01 = __float_as_uint(g1[2]);
  const float q0v = bf2f(p01 & 0xffffu);
  const float q1v = bf2f(p01 >> 16);
  const float q2v = bf2f(__float_as_uint(g1[3]) & 0xffffu);

  const unsigned selA = (lane & 1) ? 0x07030501u : 0x02060004u;
  const unsigned selB = (lane & 2) ? 0x07060302u : 0x01000504u;

  float hreg[2] = {0.f, 0.f};

  // xw block for (bg, w): 64 lanes x 2 el ushorts; lane loads 1 dword
  const ushort* xwb = xw2 + ((size_t)bg * 8 + w) * 128 + lane * 2;
  unsigned xv = *(const unsigned*)xwb;
  unsigned xn;
  __syncthreads();

#pragma clang loop unroll(disable)
  for (int t = 0; t < T_; ++t) {
    const int tn = (t + 1) & 127;
    xn = *(const unsigned*)(xwb + (size_t)tn * XW_T_STRIDE);

    const char* bufr = (const char*)(hl4 + (t & 1) * 2112);
    int4i acc[4];
    const int4i izero = {0, 0, 0, 0};
#pragma unroll
    for (int nt = 0; nt < 4; ++nt) acc[nt] = izero;
#pragma unroll
    for (int kt = 0; kt < 8; ++kt) {
      int4i a = *(const int4i*)(bufr + col16 * 528 + kt * 64 + quad * 16);
#pragma unroll
      for (int nt = 0; nt < 4; ++nt)
        acc[nt] = __builtin_amdgcn_mfma_i32_16x16x64_i8(a, bfr[kt][nt], acc[nt], 0, 0, 0);
    }
    // quad-spread: lane (quad,col16) needs acc[nt=quad][rg] from lane
    // (quad0,col16) -- rows 0,1 live in quad0's rg0,rg1.
    int accq[2];
#pragma unroll
    for (int rg = 0; rg < 2; ++rg) {
      int t0 = __shfl(acc[0][rg], col16, 64);
      int t1 = __shfl(acc[1][rg], col16, 64);
      int t2 = __shfl(acc[2][rg], col16, 64);
      int t3 = __shfl(acc[3][rg], col16, 64);
      int sA = (quad & 1) ? t1 : t0;
      int sB = (quad & 1) ? t3 : t2;
      accq[rg] = (quad & 2) ? sB : sA;
    }

    int qb[2];
#pragma unroll
    for (int rg = 0; rg < 2; ++rg) {
      float v = __uint_as_float(rg ? (xv & 0xffff0000u) : (xv << 16));
      float z = v + bcol + (float)accq[rg] * scl;
      float e = fexp2(v * (2.f * LOG2E));
      float nw = 1.f - 2.f * frcp(1.f + e);            // tanh(v)
      float d0 = z - c0v, d1 = z - c1v, d2 = z - c2v;
      float m0 = fexp2(d0 * d0 * a0v);
      float m1 = fexp2(d1 * d1 * a1v);
      float m2 = fexp2(d2 * d2 * a2v);
      float num = m0 * q0v + m1 * q1v + m2 * q2v;
      float den = m0 + m1 + m2 + 1e-8f;
      float s = num * frcp(den);
      float gg = frcp(1.f + fexp2(-s * LOG2E));        // sigmoid(s)
      float h = hreg[rg] + gg * (nw - hreg[rg]);
      hreg[rg] = h;
      qb[rg] = (int)rintf(h * 127.f);
    }

    if (t < T_ - 1) {
      // pack rows 0,1 (bytes 2,3 zero) and 4x4-transpose within col16&3
      // groups; lanes land on row (col16&3) (rows 2,3 write zeros).
      int pk = (qb[0] & 255) | ((qb[1] & 255) << 8);
      int p1 = __shfl_xor(pk, 1, 64);
      int Aw = __builtin_amdgcn_perm((unsigned)pk, (unsigned)p1, selA);
      int p2 = __shfl_xor(Aw, 2, 64);
      int Tw = __builtin_amdgcn_perm((unsigned)Aw, (unsigned)p2, selB);
      int* bufw = hl4 + (((t + 1) & 1) * 2112);
      bufw[(col16 & 3) * 132 + w * 16 + quad * 4 + (col16 >> 2)] = Tw;
      __syncthreads();
    }
    xv = xn;
  }

  // logits: sum over this wave's 64 cols, then across 8 waves
  float part[2];
#pragma unroll
  for (int rg = 0; rg < 2; ++rg) {
    part[rg] = hreg[rg] * wcl;
#pragma unroll
    for (int m = 1; m < 64; m <<= 1) part[rg] += __shfl_xor(part[rg], m, 64);
  }
  if (lane == 0) {
    red[w][0] = part[0];
    red[w][1] = part[1];
  }
  __syncthreads();
  if (tid < 2) {
    float s = bc[0];
#pragma unroll
    for (int ww = 0; ww < 8; ++ww) s += red[ww][tid];
    out[bg * 2 + tid] = s;
  }
}

extern "C" void kernel_launch(void* const* d_in, const int* in_sizes, int n_in,
                              void* d_out, int out_size, void* d_ws, size_t ws_size,
                              hipStream_t stream) {
  const float* x     = (const float*)d_in[0];
  const float* theta = (const float*)d_in[1];
  const float* Wx    = (const float*)d_in[2];
  const float* Wh    = (const float*)d_in[3];
  const float* b     = (const float*)d_in[4];
  const float* c     = (const float*)d_in[5];
  const float* sigma = (const float*)d_in[6];
  const float* q     = (const float*)d_in[7];
  const float* Wc    = (const float*)d_in[8];
  const float* bc    = (const float*)d_in[9];
  float* out = (float*)d_out;

  ushort* xw2 = (ushort*)d_ws;
  int*    W2  = (int*)((char*)d_ws + WS_W2I8);
  ushort* WxF = (ushort*)((char*)d_ws + WS_WXF);
  float*  gp8 = (float*)((char*)d_ws + WS_GP8);
  float*  bv  = (float*)((char*)d_ws + WS_BVEC);
  float*  wcv = (float*)((char*)d_ws + WS_WCV);
  float*  scl = (float*)((char*)d_ws + WS_SCOL);
  float*  inv = (float*)((char*)d_ws + WS_INVS);
  float*  wts = (float*)((char*)d_ws + WS_WTS);

  hipLaunchKernelGGL(prep_misc, dim3(512), dim3(256), 0, stream,
                     theta, Wx, b, c, sigma, q, Wc, out + B_, WxF, gp8, bv, wcv, wts);
  hipLaunchKernelGGL(scales_kernel, dim3(512), dim3(64), 0, stream, Wh, scl, inv);
  hipLaunchKernelGGL(w2i8_kernel, dim3(256), dim3(256), 0, stream, Wh, inv, W2);
  hipLaunchKernelGGL(gemm1_kernel, dim3(128, 8), dim3(256), 0, stream,
                     x, wts, WxF, xw2);
  hipLaunchKernelGGL(scan4_kernel, dim3(256), dim3(512), 0, stream,
                     xw2, (const int4i*)W2, gp8, bv, wcv, scl, bc, out);
}

// Round 8
// 275.164 us; speedup vs baseline: 7.0541x; 1.3389x over previous
//
#include <hip/hip_runtime.h>
#include <hip/hip_bf16.h>

// ---------------------------------------------------------------------------
// DRSAR_FL_RNN: B=512, T=128, F=256, H=512, K=3
// R8 = R7 scan (unchanged) + gemm1 de-serialized (batched B-frag loads via
// explicit bfv[16] array + launch_bounds(256,1); VGPR 68 was forcing ONE
// outstanding load/wave) + coalesced stage-A + prep suite rebuilt (merged
// scales/quant kernel with coalesced reads; LDS-transpose WxF; tiny prep).
// ---------------------------------------------------------------------------

#define B_  512
#define T_  128
#define F_  256
#define H_  512
#define LOG2E 1.4426950408889634f

// xw2 per-timestep stride in ushorts: [256 bg][8 w][64 lane][2 el]
#define XW_T_STRIDE 262144

typedef __attribute__((ext_vector_type(8))) short short8;
typedef __attribute__((ext_vector_type(4))) float float4v;
typedef __attribute__((ext_vector_type(4))) int int4i;

__device__ inline ushort f2bf(float f) {
  __hip_bfloat16 h = __float2bfloat16(f);
  return *reinterpret_cast<ushort*>(&h);
}
__device__ inline float bf2f(unsigned u) { return __uint_as_float(u << 16); }
__device__ inline float fexp2(float x) { return __builtin_amdgcn_exp2f(x); }
__device__ inline float frcp(float x) { return __builtin_amdgcn_rcpf(x); }

// ws layout (bytes):
//   xw2  bf16 [T][256 bg][8 w][64 lane][2 el]          : 0 .. 67108864
//   W2I8 i8 frag-linear [8 kt][32 nb][64 lane][16 B]   : 67108864 (262144)
//   WXF  bf16 frag-linear [8 kt][32 nb][64 lane][8]    : 67371008 (262144)
//   GP8  f32 [512][8]                                  : 67633152 (16384)
//   BVEC f32 [512]                                     : 67649536
//   WCV  f32 [512]                                     : 67651584
//   SCOL f32 [512]                                     : 67653632
//   WTS  f32 [256]                                     : 67657728
#define WS_W2I8 67108864
#define WS_WXF  67371008
#define WS_GP8  67633152
#define WS_BVEC 67649536
#define WS_WCV  67651584
#define WS_SCOL 67653632
#define WS_WTS  67657728

// tiny per-element prep: weights=sigmoid(theta), gating constants, b, Wc
__global__ void prep_small(const float* __restrict__ theta,
                           const float* __restrict__ b,
                           const float* __restrict__ c,
                           const float* __restrict__ sigma,
                           const float* __restrict__ q,
                           const float* __restrict__ Wc,
                           float* __restrict__ out_w,
                           float* __restrict__ gp8,
                           float* __restrict__ bvec,
                           float* __restrict__ wcv,
                           float* __restrict__ wts) {
  const int i = threadIdx.x;  // 512 threads
  if (i < F_) {
    float w = 1.f / (1.f + __expf(-theta[i]));
    out_w[i] = w;
    wts[i] = w;
  }
  {
    float a[3], cc[3], qq[3];
#pragma unroll
    for (int k = 0; k < 3; ++k) {
      float s = sigma[i * 3 + k];
      cc[k] = c[i * 3 + k];
      a[k] = -LOG2E / (2.f * s * s + 1e-8f);
      qq[k] = q[i * 3 + k];
    }
    gp8[i * 8 + 0] = cc[0];
    gp8[i * 8 + 1] = cc[1];
    gp8[i * 8 + 2] = cc[2];
    gp8[i * 8 + 3] = a[0];
    gp8[i * 8 + 4] = a[1];
    gp8[i * 8 + 5] = a[2];
    gp8[i * 8 + 6] = __uint_as_float((unsigned)f2bf(qq[0]) |
                                     ((unsigned)f2bf(qq[1]) << 16));
    gp8[i * 8 + 7] = __uint_as_float((unsigned)f2bf(qq[2]));
    bvec[i] = b[i];
    wcv[i] = Wc[i];
  }
}

// blocks 0-31: Wh column-scales + i8 quant (frag-linear W2), coalesced reads.
// blocks 32-39: Wx -> WxF bf16 frag-linear via LDS transpose.
__global__ __launch_bounds__(256) void prep_weights(
    const float* __restrict__ Wh, const float* __restrict__ Wx,
    int* __restrict__ W2, ushort* __restrict__ WxF,
    float* __restrict__ scol) {
  __shared__ float lds[16544];  // 66176 B; reused by both roles
  const int t = threadIdx.x;

  if (blockIdx.x < 32) {
    const int nb = blockIdx.x;
    // phase 1: column absmax over 16 cols, coalesced 64B runs
    const int cc = t & 15, rg = t >> 4;
    float m = 0.f;
#pragma unroll
    for (int s = 0; s < 32; ++s)
      m = fmaxf(m, fabsf(Wh[(rg + s * 16) * H_ + nb * 16 + cc]));
    lds[rg * 16 + cc] = m;
    __syncthreads();
    if (t < 16) {
      float mm = lds[t];
#pragma unroll
      for (int s = 1; s < 16; ++s) mm = fmaxf(mm, lds[s * 16 + t]);
      mm = fmaxf(mm, 1e-20f);
      scol[nb * 16 + t] = mm / (127.f * 127.f);
      lds[256 + t] = 127.f / mm;
    }
    __syncthreads();
    // phase 2: quantize, W2 layout identical to R7
    const int lane = t & 63, dw = t >> 6;
    const int n = nb * 16 + (lane & 15);
    const float iv = lds[256 + (lane & 15)];
#pragma unroll
    for (int kt = 0; kt < 8; ++kt) {
      int pk = 0;
#pragma unroll
      for (int jj = 0; jj < 4; ++jj) {
        const int k = kt * 64 + ((lane >> 4) << 4) + dw * 4 + jj;
        int qv = (int)rintf(Wh[k * H_ + n] * iv);
        qv = min(127, max(-127, qv));
        pk |= (qv & 255) << (8 * jj);
      }
      W2[((kt * 32 + nb) * 64 + lane) * 4 + dw] = pk;
    }
  } else {
    const int kt = blockIdx.x - 32;
    // stage Wx rows [kt*32, kt*32+32) x 512 into LDS, row stride 517
#pragma unroll
    for (int it = 0; it < 16; ++it) {
      const int lin = (it * 256 + t) * 4;
      const float4 v = *(const float4*)(Wx + kt * 32 * H_ + lin);
      const int f = lin >> 9, n0 = lin & 511;
      lds[f * 517 + n0 + 0] = v.x;
      lds[f * 517 + n0 + 1] = v.y;
      lds[f * 517 + n0 + 2] = v.z;
      lds[f * 517 + n0 + 3] = v.w;
    }
    __syncthreads();
    // write frag-linear: o = (nb*64+lane)*8 + j, coalesced 16B/lane runs
#pragma unroll
    for (int it = 0; it < 8; ++it) {
      const int o = (it * 256 + t) * 8;
      const int lane = (o >> 3) & 63, nb = o >> 9;
      const int n = nb * 16 + (lane & 15), fb = (lane >> 4) << 3;
      ushort v[8];
#pragma unroll
      for (int j = 0; j < 8; ++j) v[j] = f2bf(lds[(fb + j) * 517 + n]);
      *(short8*)(WxF + kt * 16384 + o) = *(short8*)v;
    }
  }
}

// xw2 = bf16(x*wts) @ bf16(Wx), stored in scan4's layout.
// grid (t=128, bblk64=8), 256 thr. Batched B-frag loads (16 in flight).
__global__ __launch_bounds__(256, 1) void gemm1_kernel(
    const float* __restrict__ x, const float* __restrict__ wts,
    const ushort* __restrict__ WxF, ushort* __restrict__ xw2) {
  __shared__ ushort A[64 * 264];
  const int tid = threadIdx.x;
  const int lane = tid & 63, wg = tid >> 6;
  const int col16 = lane & 15, quad = lane >> 4;
  const int tt = blockIdx.x, bb = blockIdx.y;

  {  // stage A coalesced: wave reads one contiguous 1KB row per iteration
    const float4 wv = *(const float4*)(wts + lane * 4);
#pragma unroll
    for (int it = 0; it < 16; ++it) {
      const int row = it * 4 + wg;
      float4 xv = *(const float4*)(x + ((size_t)(bb * 64 + row) * T_ + tt) * F_ + lane * 4);
      ushort4 o;
      o.x = f2bf(xv.x * wv.x);
      o.y = f2bf(xv.y * wv.y);
      o.z = f2bf(xv.z * wv.z);
      o.w = f2bf(xv.w * wv.w);
      *(ushort4*)&A[row * 264 + lane * 4] = o;
    }
  }
  __syncthreads();

  const float4v zero = {0.f, 0.f, 0.f, 0.f};
#pragma unroll
  for (int nn = 0; nn < 2; ++nn) {
    float4v acc[16];
#pragma unroll
    for (int i = 0; i < 16; ++i) acc[i] = zero;
#pragma unroll
    for (int kt = 0; kt < 8; ++kt) {
      short8 af = *(const short8*)&A[(wg * 16 + col16) * 264 + kt * 32 + quad * 8];
      short8 bfv[16];
#pragma unroll
      for (int nt = 0; nt < 16; ++nt)
        bfv[nt] = *(const short8*)(WxF + ((kt * 32 + nn * 16 + nt) * 64 + lane) * 8);
#pragma unroll
      for (int nt = 0; nt < 16; ++nt)
        acc[nt] = __builtin_amdgcn_mfma_f32_16x16x32_bf16(af, bfv[nt], acc[nt], 0, 0, 0);
    }
    // store into scan4 layout (unchanged from R7)
#pragma unroll
    for (int nt = 0; nt < 16; ++nt) {
      ushort2 lo, hi;
      lo.x = f2bf(acc[nt][0]);
      lo.y = f2bf(acc[nt][1]);
      hi.x = f2bf(acc[nt][2]);
      hi.y = f2bf(acc[nt][3]);
      const int bg0 = bb * 32 + wg * 8 + quad * 2;
      const size_t off0 =
          (((size_t)tt * 256 + bg0) * 8 + nn * 4 + (nt >> 2)) * 128 +
          ((nt & 3) * 16 + col16) * 2;
      *(ushort2*)(xw2 + off0) = lo;
      *(ushort2*)(xw2 + off0 + 1024) = hi;  // bg0+1
    }
  }
}

// scan4: 256 WGs x 512 thr (8 waves); WG owns 2 batch rows; wave owns 64
// cols. Quad-spread via shfl; each lane owns ONE h-column, 2 elements.
// Double-buffered LDS h-mirror (rows 2-15 zero), one barrier/step.
__global__ __launch_bounds__(512, 2) void scan4_kernel(
    const ushort* __restrict__ xw2, const int4i* __restrict__ W2,
    const float* __restrict__ gp8, const float* __restrict__ bvec,
    const float* __restrict__ wcv, const float* __restrict__ scol,
    const float* __restrict__ bc, float* __restrict__ out) {
  __shared__ int hl4[2 * 16 * 132];
  __shared__ float red[8][2];
  const int tid = threadIdx.x;
  const int lane = tid & 63, w = tid >> 6;
  const int col16 = lane & 15, quad = lane >> 4;
  const int bg = blockIdx.x;

  for (int i = tid; i < 2 * 16 * 132; i += 512) hl4[i] = 0;

  int4i bfr[8][4];
#pragma unroll
  for (int kt = 0; kt < 8; ++kt)
#pragma unroll
    for (int nt = 0; nt < 4; ++nt)
      bfr[kt][nt] = W2[(kt * 32 + w * 4 + nt) * 64 + lane];

  const int col = w * 64 + lane;
  const float bcol = bvec[col], scl = scol[col], wcl = wcv[col];
  float4v g0 = *(const float4v*)(gp8 + col * 8);
  float4v g1 = *(const float4v*)(gp8 + col * 8 + 4);
  const float c0v = g0[0], c1v = g0[1], c2v = g0[2];
  const float a0v = g0[3], a1v = g1[0], a2v = g1[1];
  unsigned p01 = __float_as_uint(g1[2]);
  const float q0v = bf2f(p01 & 0xffffu);
  const float q1v = bf2f(p01 >> 16);
  const float q2v = bf2f(__float_as_uint(g1[3]) & 0xffffu);

  const unsigned selA = (lane & 1) ? 0x07030501u : 0x02060004u;
  const unsigned selB = (lane & 2) ? 0x07060302u : 0x01000504u;

  float hreg[2] = {0.f, 0.f};

  const ushort* xwb = xw2 + ((size_t)bg * 8 + w) * 128 + lane * 2;
  unsigned xv = *(const unsigned*)xwb;
  unsigned xn;
  __syncthreads();

#pragma clang loop unroll(disable)
  for (int t = 0; t < T_; ++t) {
    const int tn = (t + 1) & 127;
    xn = *(const unsigned*)(xwb + (size_t)tn * XW_T_STRIDE);

    const char* bufr = (const char*)(hl4 + (t & 1) * 2112);
    int4i acc[4];
    const int4i izero = {0, 0, 0, 0};
#pragma unroll
    for (int nt = 0; nt < 4; ++nt) acc[nt] = izero;
#pragma unroll
    for (int kt = 0; kt < 8; ++kt) {
      int4i a = *(const int4i*)(bufr + col16 * 528 + kt * 64 + quad * 16);
#pragma unroll
      for (int nt = 0; nt < 4; ++nt)
        acc[nt] = __builtin_amdgcn_mfma_i32_16x16x64_i8(a, bfr[kt][nt], acc[nt], 0, 0, 0);
    }
    int accq[2];
#pragma unroll
    for (int rg = 0; rg < 2; ++rg) {
      int t0 = __shfl(acc[0][rg], col16, 64);
      int t1 = __shfl(acc[1][rg], col16, 64);
      int t2 = __shfl(acc[2][rg], col16, 64);
      int t3 = __shfl(acc[3][rg], col16, 64);
      int sA = (quad & 1) ? t1 : t0;
      int sB = (quad & 1) ? t3 : t2;
      accq[rg] = (quad & 2) ? sB : sA;
    }

    int qb[2];
#pragma unroll
    for (int rg = 0; rg < 2; ++rg) {
      float v = __uint_as_float(rg ? (xv & 0xffff0000u) : (xv << 16));
      float z = v + bcol + (float)accq[rg] * scl;
      float e = fexp2(v * (2.f * LOG2E));
      float nw = 1.f - 2.f * frcp(1.f + e);            // tanh(v)
      float d0 = z - c0v, d1 = z - c1v, d2 = z - c2v;
      float m0 = fexp2(d0 * d0 * a0v);
      float m1 = fexp2(d1 * d1 * a1v);
      float m2 = fexp2(d2 * d2 * a2v);
      float num = m0 * q0v + m1 * q1v + m2 * q2v;
      float den = m0 + m1 + m2 + 1e-8f;
      float s = num * frcp(den);
      float gg = frcp(1.f + fexp2(-s * LOG2E));        // sigmoid(s)
      float h = hreg[rg] + gg * (nw - hreg[rg]);
      hreg[rg] = h;
      qb[rg] = (int)rintf(h * 127.f);
    }

    if (t < T_ - 1) {
      int pk = (qb[0] & 255) | ((qb[1] & 255) << 8);
      int p1 = __shfl_xor(pk, 1, 64);
      int Aw = __builtin_amdgcn_perm((unsigned)pk, (unsigned)p1, selA);
      int p2 = __shfl_xor(Aw, 2, 64);
      int Tw = __builtin_amdgcn_perm((unsigned)Aw, (unsigned)p2, selB);
      int* bufw = hl4 + (((t + 1) & 1) * 2112);
      bufw[(col16 & 3) * 132 + w * 16 + quad * 4 + (col16 >> 2)] = Tw;
      __syncthreads();
    }
    xv = xn;
  }

  float part[2];
#pragma unroll
  for (int rg = 0; rg < 2; ++rg) {
    part[rg] = hreg[rg] * wcl;
#pragma unroll
    for (int m = 1; m < 64; m <<= 1) part[rg] += __shfl_xor(part[rg], m, 64);
  }
  if (lane == 0) {
    red[w][0] = part[0];
    red[w][1] = part[1];
  }
  __syncthreads();
  if (tid < 2) {
    float s = bc[0];
#pragma unroll
    for (int ww = 0; ww < 8; ++ww) s += red[ww][tid];
    out[bg * 2 + tid] = s;
  }
}

extern "C" void kernel_launch(void* const* d_in, const int* in_sizes, int n_in,
                              void* d_out, int out_size, void* d_ws, size_t ws_size,
                              hipStream_t stream) {
  const float* x     = (const float*)d_in[0];
  const float* theta = (const float*)d_in[1];
  const float* Wx    = (const float*)d_in[2];
  const float* Wh    = (const float*)d_in[3];
  const float* b     = (const float*)d_in[4];
  const float* c     = (const float*)d_in[5];
  const float* sigma = (const float*)d_in[6];
  const float* q     = (const float*)d_in[7];
  const float* Wc    = (const float*)d_in[8];
  const float* bc    = (const float*)d_in[9];
  float* out = (float*)d_out;

  ushort* xw2 = (ushort*)d_ws;
  int*    W2  = (int*)((char*)d_ws + WS_W2I8);
  ushort* WxF = (ushort*)((char*)d_ws + WS_WXF);
  float*  gp8 = (float*)((char*)d_ws + WS_GP8);
  float*  bv  = (float*)((char*)d_ws + WS_BVEC);
  float*  wcv = (float*)((char*)d_ws + WS_WCV);
  float*  scl = (float*)((char*)d_ws + WS_SCOL);
  float*  wts = (float*)((char*)d_ws + WS_WTS);

  hipLaunchKernelGGL(prep_small, dim3(1), dim3(512), 0, stream,
                     theta, b, c, sigma, q, Wc, out + B_, gp8, bv, wcv, wts);
  hipLaunchKernelGGL(prep_weights, dim3(40), dim3(256), 0, stream,
                     Wh, Wx, W2, WxF, scl);
  hipLaunchKernelGGL(gemm1_kernel, dim3(128, 8), dim3(256), 0, stream,
                     x, wts, WxF, xw2);
  hipLaunchKernelGGL(scan4_kernel, dim3(256), dim3(512), 0, stream,
                     xw2, (const int4i*)W2, gp8, bv, wcv, scl, bc, out);
}